// Round 1
// baseline (501.373 us; speedup 1.0000x reference)
//
#include <hip/hip_runtime.h>
#include <math.h>

// Problem dims (fixed by the reference)
#define B_TOK 4096
#define S_TOK 197
#define D_TOK 768
#define E_EXP 16

// Flat output offsets (float32 elements), concatenated in return order:
// router_logits (4096x16), selected_experts (4096x2), expert_weights (4096x16), load (16)
#define SE_OFF   (B_TOK * E_EXP)              // 65536
#define EW_OFF   (SE_OFF + B_TOK * 2)         // 73728
#define LOAD_OFF (EW_OFF + B_TOK * E_EXP)     // 139264

__device__ __forceinline__ float softplusf(float x) {
    // numerically-stable log(1+exp(x)) == logaddexp(x, 0)
    return fmaxf(x, 0.0f) + log1pf(expf(-fabsf(x)));
}

__global__ __launch_bounds__(192) void gate_kernel(
    const float* __restrict__ tokens,
    const float* __restrict__ noise,
    const float* __restrict__ w_gate,
    const float* __restrict__ w_noise,
    float* __restrict__ out,
    float* __restrict__ prob_ws) // [B_TOK][E_EXP]
{
    const int b    = blockIdx.x;
    const int t    = threadIdx.x;   // 0..191, thread t owns columns 4t..4t+3
    const int lane = t & 63;
    const int wid  = t >> 6;        // 0..2

    // ---- pooled mean: coalesced float4 loads over all S rows ----
    const float4* tok = reinterpret_cast<const float4*>(
        tokens + (size_t)b * (size_t)(S_TOK * D_TOK));
    float4 acc = make_float4(0.f, 0.f, 0.f, 0.f);
    #pragma unroll 4
    for (int s = 0; s < S_TOK; ++s) {
        float4 v = tok[(size_t)s * (D_TOK / 4) + t];
        acc.x += v.x; acc.y += v.y; acc.z += v.z; acc.w += v.w;
    }
    const float inv_s = 1.0f / (float)S_TOK;
    float pv[4] = { acc.x * inv_s, acc.y * inv_s, acc.z * inv_s, acc.w * inv_s };

    // ---- per-thread partial dot products: 16 gate + 16 noise ----
    float pg[E_EXP], pn[E_EXP];
    #pragma unroll
    for (int e = 0; e < E_EXP; ++e) { pg[e] = 0.f; pn[e] = 0.f; }

    #pragma unroll
    for (int j = 0; j < 4; ++j) {
        const int d = t * 4 + j;
        const float4* wg = reinterpret_cast<const float4*>(w_gate  + (size_t)d * E_EXP);
        const float4* wn = reinterpret_cast<const float4*>(w_noise + (size_t)d * E_EXP);
        const float p = pv[j];
        #pragma unroll
        for (int q = 0; q < 4; ++q) {
            float4 g = wg[q];
            float4 n = wn[q];
            pg[q*4+0] += p * g.x; pg[q*4+1] += p * g.y;
            pg[q*4+2] += p * g.z; pg[q*4+3] += p * g.w;
            pn[q*4+0] += p * n.x; pn[q*4+1] += p * n.y;
            pn[q*4+2] += p * n.z; pn[q*4+3] += p * n.w;
        }
    }

    // ---- reduce 32 values across the block (wave shuffle -> tiny LDS) ----
    __shared__ float red[3][32];
    __shared__ float tot[32];
    __shared__ float s_rl[E_EXP], s_clean[E_EXP], s_std[E_EXP];
    __shared__ float s_scal[4];  // [0]=thr_out(v1), [1]=thr_in(v2), [2]=w0, [3]=w1
    __shared__ int   s_idx[2];

    #pragma unroll
    for (int v = 0; v < 32; ++v) {
        float x = (v < 16) ? pg[v] : pn[v - 16];
        x += __shfl_down(x, 32);
        x += __shfl_down(x, 16);
        x += __shfl_down(x, 8);
        x += __shfl_down(x, 4);
        x += __shfl_down(x, 2);
        x += __shfl_down(x, 1);
        if (lane == 0) red[wid][v] = x;
    }
    __syncthreads();

    if (t < 32) tot[t] = red[0][t] + red[1][t] + red[2][t];
    __syncthreads();

    if (t < 16) {
        float clean = tot[t];
        float sd    = softplusf(tot[16 + t]) + 0.01f;   // NOISE_EPS
        float rl    = clean + noise[(size_t)b * E_EXP + t] * sd;
        out[(size_t)b * E_EXP + t] = rl;                // router_logits
        s_rl[t]    = rl;
        s_clean[t] = clean;
        s_std[t]   = sd;
    }
    __syncthreads();

    if (t == 0) {
        // top-3 with lower-index-wins tie-break (matches jax.lax.top_k)
        float v0 = -INFINITY, v1 = -INFINITY, v2 = -INFINITY;
        int   i0 = 0, i1 = 0;
        #pragma unroll
        for (int e = 0; e < E_EXP; ++e) {
            float v = s_rl[e];
            if (v > v0)      { v2 = v1; v1 = v0; i1 = i0; v0 = v; i0 = e; }
            else if (v > v1) { v2 = v1; v1 = v; i1 = e; }
            else if (v > v2) { v2 = v; }
        }
        float e1 = expf(v1 - v0);
        float w0 = 1.0f / (1.0f + e1);
        float w1 = e1   / (1.0f + e1);
        s_scal[0] = v1; s_scal[1] = v2; s_scal[2] = w0; s_scal[3] = w1;
        s_idx[0] = i0; s_idx[1] = i1;
        out[SE_OFF + (size_t)b * 2 + 0] = (float)i0;    // selected_experts
        out[SE_OFF + (size_t)b * 2 + 1] = (float)i1;
    }
    __syncthreads();

    if (t < 16) {
        const float thr_out_v = s_scal[0];
        const float thr_in_v  = s_scal[1];
        float w = (t == s_idx[0]) ? s_scal[2] : ((t == s_idx[1]) ? s_scal[3] : 0.0f);
        out[EW_OFF + (size_t)b * E_EXP + t] = w;        // expert_weights

        float thr = (s_rl[t] > thr_in_v) ? thr_in_v : thr_out_v;
        float x   = (s_clean[t] - thr) / s_std[t];
        prob_ws[(size_t)b * E_EXP + t] = 0.5f * (1.0f + erff(x * 0.70710678118654752f));
    }
}

__global__ __launch_bounds__(256) void load_kernel(
    const float* __restrict__ prob_ws,
    float* __restrict__ out_load)
{
    const int e = blockIdx.x;      // expert 0..15
    const int t = threadIdx.x;     // 0..255
    float s = 0.f;
    for (int r = t; r < B_TOK; r += 256)
        s += prob_ws[(size_t)r * E_EXP + e];
    s += __shfl_down(s, 32);
    s += __shfl_down(s, 16);
    s += __shfl_down(s, 8);
    s += __shfl_down(s, 4);
    s += __shfl_down(s, 2);
    s += __shfl_down(s, 1);
    __shared__ float red[4];
    if ((t & 63) == 0) red[t >> 6] = s;
    __syncthreads();
    if (t == 0) out_load[e] = red[0] + red[1] + red[2] + red[3];
}

extern "C" void kernel_launch(void* const* d_in, const int* in_sizes, int n_in,
                              void* d_out, int out_size, void* d_ws, size_t ws_size,
                              hipStream_t stream) {
    (void)in_sizes; (void)n_in; (void)out_size; (void)ws_size;
    const float* tokens  = (const float*)d_in[0];
    const float* noise   = (const float*)d_in[1];
    const float* w_gate  = (const float*)d_in[2];
    const float* w_noise = (const float*)d_in[3];
    float* out = (float*)d_out;
    float* ws  = (float*)d_ws;   // needs 4096*16*4 = 256 KB

    gate_kernel<<<B_TOK, 192, 0, stream>>>(tokens, noise, w_gate, w_noise, out, ws);
    load_kernel<<<E_EXP, 256, 0, stream>>>(ws, out + LOAD_OFF);
}

// Round 2
// 380.825 us; speedup vs baseline: 1.3165x; 1.3165x over previous
//
#include <hip/hip_runtime.h>
#include <math.h>

// Problem dims (fixed by the reference)
#define B_TOK 4096
#define S_TOK 197
#define D_TOK 768
#define E_EXP 16

// Flat output offsets (float32 elements), concatenated in return order:
// router_logits (4096x16), selected_experts (4096x2), expert_weights (4096x16), load (16)
#define SE_OFF   (B_TOK * E_EXP)              // 65536
#define EW_OFF   (SE_OFF + B_TOK * 2)         // 73728
#define LOAD_OFF (EW_OFF + B_TOK * E_EXP)     // 139264

typedef float f32x4 __attribute__((ext_vector_type(4)));

__device__ __forceinline__ f32x4 ntload(const f32x4* p) {
    return __builtin_nontemporal_load(p);
}

__device__ __forceinline__ float softplusf(float x) {
    return fmaxf(x, 0.0f) + log1pf(expf(-fabsf(x)));
}

// One block = 2 batch rows. 192 threads (3 waves).
// Phase 1: stream-pool both rows into LDS (low-VGPR, 8 loads in flight).
// Phase 2: GEMV (32 outputs x 768) from LDS pooled + L2-resident weights.
// Phase 3: per-row epilogue (softplus, router logits, top-3, softmax, cdf).
__global__ __launch_bounds__(192, 8) void gate_kernel(
    const float* __restrict__ tokens,
    const float* __restrict__ noise,
    const float* __restrict__ w_gate,
    const float* __restrict__ w_noise,
    float* __restrict__ out,
    float* __restrict__ prob_ws) // [B_TOK][E_EXP]
{
    const int b0 = blockIdx.x * 2;
    const int b1 = b0 + 1;
    const int t  = threadIdx.x;   // 0..191; thread owns float4-column t of both rows

    __shared__ float pooled[2][D_TOK];          // 6 KB
    __shared__ float part[2 * 192];             // [r][g*32+o]
    __shared__ float s_tot[2 * 32];
    __shared__ float s_rl[2][E_EXP], s_clean[2][E_EXP], s_std[2][E_EXP];
    __shared__ float s_scal[2][4];              // thr_out(v1), thr_in(v2), w0, w1
    __shared__ int   s_idx[2][2];

    // ---- Phase 1: pooled mean, 2 rows, 8 nontemporal loads in flight ----
    {
        const f32x4* tok0 = reinterpret_cast<const f32x4*>(
            tokens + (size_t)b0 * (size_t)(S_TOK * D_TOK)) + t;
        const f32x4* tok1 = reinterpret_cast<const f32x4*>(
            tokens + (size_t)b1 * (size_t)(S_TOK * D_TOK)) + t;
        f32x4 acc0 = (f32x4)0.0f;
        f32x4 acc1 = (f32x4)0.0f;
        int s = 0;
        for (; s + 4 <= S_TOK; s += 4) {
            f32x4 a0 = ntload(tok0 + (size_t)(s + 0) * (D_TOK / 4));
            f32x4 a1 = ntload(tok0 + (size_t)(s + 1) * (D_TOK / 4));
            f32x4 a2 = ntload(tok0 + (size_t)(s + 2) * (D_TOK / 4));
            f32x4 a3 = ntload(tok0 + (size_t)(s + 3) * (D_TOK / 4));
            f32x4 c0 = ntload(tok1 + (size_t)(s + 0) * (D_TOK / 4));
            f32x4 c1 = ntload(tok1 + (size_t)(s + 1) * (D_TOK / 4));
            f32x4 c2 = ntload(tok1 + (size_t)(s + 2) * (D_TOK / 4));
            f32x4 c3 = ntload(tok1 + (size_t)(s + 3) * (D_TOK / 4));
            acc0 += (a0 + a1) + (a2 + a3);
            acc1 += (c0 + c1) + (c2 + c3);
        }
        for (; s < S_TOK; ++s) {
            acc0 += ntload(tok0 + (size_t)s * (D_TOK / 4));
            acc1 += ntload(tok1 + (size_t)s * (D_TOK / 4));
        }
        const float inv_s = 1.0f / (float)S_TOK;
        acc0 *= inv_s;
        acc1 *= inv_s;
        reinterpret_cast<f32x4*>(&pooled[0][0])[t] = acc0;
        reinterpret_cast<f32x4*>(&pooled[1][0])[t] = acc1;
    }
    __syncthreads();

    // ---- Phase 2: GEMV. o = output (0..15 gate, 16..31 noise), g = d-chunk ----
    {
        const int o = t & 31;
        const int g = t >> 5;                  // 0..5, each covers 128 d's
        const float* wptr = ((o < 16) ? w_gate : w_noise) + (o & 15);
        const int dbase = g * 128;
        float sum0 = 0.f, sum1 = 0.f;
        #pragma unroll 8
        for (int k = 0; k < 128; ++k) {
            const int d = dbase + k;
            float wv = wptr[(size_t)d * E_EXP];
            sum0 = fmaf(pooled[0][d], wv, sum0);
            sum1 = fmaf(pooled[1][d], wv, sum1);
        }
        part[0 * 192 + g * 32 + o] = sum0;
        part[1 * 192 + g * 32 + o] = sum1;
    }
    __syncthreads();

    if (t < 64) {
        const int r = t >> 5;
        const int o = t & 31;
        const float* p = &part[r * 192 + o];
        s_tot[r * 32 + o] = p[0] + p[32] + p[64] + p[96] + p[128] + p[160];
    }
    __syncthreads();

    // ---- Phase 3: epilogue ----
    if (t < 32) {
        const int r = t >> 4;
        const int e = t & 15;
        const int b = b0 + r;
        float clean = s_tot[r * 32 + e];
        float sd    = softplusf(s_tot[r * 32 + 16 + e]) + 0.01f;  // NOISE_EPS
        float rl    = clean + noise[(size_t)b * E_EXP + e] * sd;
        out[(size_t)b * E_EXP + e] = rl;                // router_logits
        s_rl[r][e]    = rl;
        s_clean[r][e] = clean;
        s_std[r][e]   = sd;
    }
    __syncthreads();

    if (t < 2) {
        const int r = t;
        const int b = b0 + r;
        // top-3, lower-index-wins tie-break (matches jax.lax.top_k)
        float v0 = -INFINITY, v1 = -INFINITY, v2 = -INFINITY;
        int   i0 = 0, i1 = 0;
        #pragma unroll
        for (int e = 0; e < E_EXP; ++e) {
            float v = s_rl[r][e];
            if (v > v0)      { v2 = v1; v1 = v0; i1 = i0; v0 = v; i0 = e; }
            else if (v > v1) { v2 = v1; v1 = v; i1 = e; }
            else if (v > v2) { v2 = v; }
        }
        float e1 = expf(v1 - v0);
        float w0 = 1.0f / (1.0f + e1);
        float w1 = e1   / (1.0f + e1);
        s_scal[r][0] = v1; s_scal[r][1] = v2; s_scal[r][2] = w0; s_scal[r][3] = w1;
        s_idx[r][0] = i0; s_idx[r][1] = i1;
        out[SE_OFF + (size_t)b * 2 + 0] = (float)i0;    // selected_experts
        out[SE_OFF + (size_t)b * 2 + 1] = (float)i1;
    }
    __syncthreads();

    if (t < 32) {
        const int r = t >> 4;
        const int e = t & 15;
        const int b = b0 + r;
        const float thr_out_v = s_scal[r][0];
        const float thr_in_v  = s_scal[r][1];
        float w = (e == s_idx[r][0]) ? s_scal[r][2]
                : ((e == s_idx[r][1]) ? s_scal[r][3] : 0.0f);
        out[EW_OFF + (size_t)b * E_EXP + e] = w;        // expert_weights

        float thr = (s_rl[r][e] > thr_in_v) ? thr_in_v : thr_out_v;
        float x   = (s_clean[r][e] - thr) / s_std[r][e];
        prob_ws[(size_t)b * E_EXP + e] = 0.5f * (1.0f + erff(x * 0.70710678118654752f));
    }
}

__global__ __launch_bounds__(256) void load_kernel(
    const float* __restrict__ prob_ws,
    float* __restrict__ out_load)
{
    const int e = blockIdx.x;      // expert 0..15
    const int t = threadIdx.x;     // 0..255
    float s = 0.f;
    for (int r = t; r < B_TOK; r += 256)
        s += prob_ws[(size_t)r * E_EXP + e];
    s += __shfl_down(s, 32);
    s += __shfl_down(s, 16);
    s += __shfl_down(s, 8);
    s += __shfl_down(s, 4);
    s += __shfl_down(s, 2);
    s += __shfl_down(s, 1);
    __shared__ float red[4];
    if ((t & 63) == 0) red[t >> 6] = s;
    __syncthreads();
    if (t == 0) out_load[e] = red[0] + red[1] + red[2] + red[3];
}

extern "C" void kernel_launch(void* const* d_in, const int* in_sizes, int n_in,
                              void* d_out, int out_size, void* d_ws, size_t ws_size,
                              hipStream_t stream) {
    (void)in_sizes; (void)n_in; (void)out_size; (void)ws_size;
    const float* tokens  = (const float*)d_in[0];
    const float* noise   = (const float*)d_in[1];
    const float* w_gate  = (const float*)d_in[2];
    const float* w_noise = (const float*)d_in[3];
    float* out = (float*)d_out;
    float* ws  = (float*)d_ws;   // needs 4096*16*4 = 256 KB

    gate_kernel<<<B_TOK / 2, 192, 0, stream>>>(tokens, noise, w_gate, w_noise, out, ws);
    load_kernel<<<E_EXP, 256, 0, stream>>>(ws, out + LOAD_OFF);
}